// Round 5
// baseline (430.538 us; speedup 1.0000x reference)
//
#include <hip/hip_runtime.h>

#define D_DIM 2048
#define E_NUM 64
#define M_TOK 16384          // B*L = 4*4096
#define BK 32                // k per staged tile
#define XS_ROW 36            // 32 + 4 pad: 144B row stride -> rows 16B-aligned for
                             // ds_read_b128; 8 cyc/b128 wave access (minimum)
#define XS_TILE (64 * XS_ROW)   // 2304 floats per (half, buf)

// ws layout: gprob[64], gcnt[64], Wt[2048*64] (f32, [k][e])

// one-off transpose W[e][k] -> Wt[k][e]; block 0 also zeroes gprob/gcnt
__global__ __launch_bounds__(256) void wt_kernel(const float* __restrict__ W,
                                                 float* __restrict__ Wt,
                                                 float* __restrict__ g) {
    if (blockIdx.x == 0 && threadIdx.x < 128) g[threadIdx.x] = 0.0f;
    const int i4 = blockIdx.x * 256 + threadIdx.x;   // grid 128 -> 32768 float4s
    const int e  = i4 >> 9;                          // 0..63
    const int k4 = (i4 & 511) << 2;                  // 0..2044
    const float4 v = *(const float4*)&W[e * D_DIM + k4];
    Wt[(k4 + 0) * E_NUM + e] = v.x;
    Wt[(k4 + 1) * E_NUM + e] = v.y;
    Wt[(k4 + 2) * E_NUM + e] = v.z;
    Wt[(k4 + 3) * E_NUM + e] = v.w;
}

// block = 1024 threads = 16 waves; block owns 64 tokens (lane = token).
// wave w: k-half h = w>>3, experts [8*(w&7), +8).
// R4 lesson: readfirstlane-uniform W addresses made the compiler scalarize the
// whole W stream (VGPR=28, SGPR=112) -> 1024 s_load_dwordx4/iter/CU through
// the single scalar pipe + tiny K$ = the real bottleneck (VALUBusy 31%).
// Fix: force W onto the VECTOR memory path via an asm VGPR-zero mixed into the
// base address (TCP broadcasts a uniform address; per-iter W tile = 16 KB,
// L1-resident). W in VGPRs: 16 float4/batch = 64 VGPR in flight; demand ~112
// < 128 cap (1024-thread block); unroll-1 batches prevent hoist/spill.
// LDS union (9216 floats):
//   gemm phase: xs(h,buf) at (h*2+buf)*2304, [64 rows][36]
//   epilogue:   S(h) at h*4096 + t*64 + e  (after last loop barrier, xs dead)
//   reduction:  pacc [0..256), cacc [256..512)
__global__ __launch_bounds__(1024, 1) void fused_kernel(
    const float* __restrict__ x, const float* __restrict__ Wt,
    float* __restrict__ out, float* __restrict__ gprob, float* __restrict__ gcnt)
{
    __shared__ float lds[4 * XS_TILE];   // 36864 B

    const int tid  = threadIdx.x;
    const int wid  = tid >> 6;
    const int lane = tid & 63;           // token within block
    const int h    = wid >> 3;           // k-half
    const int eb   = (wid & 7) << 3;     // expert base (8 experts/wave)
    const long tok0 = (long)blockIdx.x * 64;

    // VGPR-held zero the compiler cannot fold: keeps W addressing divergent
    // -> global_load_dwordx4 (vector path), not s_load (scalar path).
    int vz;
    asm volatile("v_mov_b32 %0, 0" : "=v"(vz));
    const float* wbase = Wt + vz;

    // staging role: threads 0..511 stage half 0, 512..1023 stage half 1;
    // one float4 per thread per tile (64 rows x 32 k per half)
    const int sh   = tid >> 9;
    const int ss   = tid & 511;
    const int srow = ss >> 3;            // token row 0..63
    const int sc   = (ss & 7) << 2;      // k offset 0,4,...,28
    const float* xsrc = x + (tok0 + srow) * D_DIM + (sh << 10) + sc;

    double accd[8];
    #pragma unroll
    for (int e = 0; e < 8; ++e) accd[e] = 0.0;

    // ---- prologue: stage tile 0 ----
    float4 v0 = *(const float4*)(xsrc);
    *(float4*)&lds[(sh * 2) * XS_TILE + srow * XS_ROW + sc] = v0;
    __syncthreads();

    for (int it = 0; it < 32; ++it) {
        // issue next tile's global load early (HBM latency hides under compute)
        if (it < 31) v0 = *(const float4*)(xsrc + (it + 1) * BK);
        // ---- compute tile it from buf (it&1) ----
        const float* xb = lds + (h * 2 + (it & 1)) * XS_TILE + lane * XS_ROW;
        const int kb0 = (h << 10) + it * BK;
        #pragma unroll 1
        for (int c2 = 0; c2 < 2; ++c2) {     // two 16-k chunks (fold granularity)
            float accc[8];
            #pragma unroll
            for (int e = 0; e < 8; ++e) accc[e] = 0.0f;
            const float* xc = xb + c2 * 16;
            const float* wp = wbase + (size_t)(kb0 + c2 * 16) * E_NUM + eb;
            #pragma unroll 1
            for (int q = 0; q < 2; ++q) {    // 8-k batches bound W in flight
                const float4 xa  = *(const float4*)(xc + q * 8);
                const float4 xs4 = *(const float4*)(xc + q * 8 + 4);
                const float xr[8] = { xa.x, xa.y, xa.z, xa.w,
                                      xs4.x, xs4.y, xs4.z, xs4.w };
                float4 w0[8], w1[8];         // 16 float4 in flight (64 VGPR)
                #pragma unroll
                for (int k2 = 0; k2 < 8; ++k2) {
                    const float* wr = wp + (q * 8 + k2) * E_NUM;
                    w0[k2] = *(const float4*)(wr + 0);
                    w1[k2] = *(const float4*)(wr + 4);
                }
                // per-expert k ascending: q outer, k2 inner -> k 0..15 in order
                #pragma unroll
                for (int k2 = 0; k2 < 8; ++k2) {
                    const float xk = xr[k2];
                    accc[0] += xk * w0[k2].x;  accc[1] += xk * w0[k2].y;
                    accc[2] += xk * w0[k2].z;  accc[3] += xk * w0[k2].w;
                    accc[4] += xk * w1[k2].x;  accc[5] += xk * w1[k2].y;
                    accc[6] += xk * w1[k2].z;  accc[7] += xk * w1[k2].w;
                }
            }
            #pragma unroll
            for (int e = 0; e < 8; ++e) accd[e] += (double)accc[e];
        }
        // ---- write staged reg into the other buffer ----
        if (it < 31)
            *(float4*)&lds[(sh * 2 + ((it + 1) & 1)) * XS_TILE + srow * XS_ROW + sc] = v0;
        __syncthreads();
    }

    // ---- S overlay: per-half f32 partial logits (same split/cast as before) ----
    {
        float* sp = lds + h * 4096 + lane * 64 + eb;
        *(float4*)(sp + 0) = make_float4((float)accd[0], (float)accd[1],
                                         (float)accd[2], (float)accd[3]);
        *(float4*)(sp + 4) = make_float4((float)accd[4], (float)accd[5],
                                         (float)accd[6], (float)accd[7]);
    }
    __syncthreads();

    // ---- fused topk/softmax (waves 0..3; lane = expert; verbatim math) ----
    float pacc = 0.0f, cacc = 0.0f;
    if (wid < 4) {
        const int q = wid;
        for (int i = 0; i < 16; ++i) {
            const int  tl = q * 16 + i;
            const long t  = tok0 + tl;
            const float l = lds[tl * 64 + lane] + lds[4096 + tl * 64 + lane];
            // top-1 (max, lowest index on tie — matches jax.lax.top_k)
            float m1 = l; int i1 = lane;
            #pragma unroll
            for (int off = 32; off > 0; off >>= 1) {
                const float ov = __shfl_xor(m1, off, 64);
                const int   oi = __shfl_xor(i1, off, 64);
                if (ov > m1 || (ov == m1 && oi < i1)) { m1 = ov; i1 = oi; }
            }
            // full softmax prob for aux loss
            const float p = __expf(l - m1);
            float s = p;
            #pragma unroll
            for (int off = 32; off > 0; off >>= 1) s += __shfl_xor(s, off, 64);
            pacc += p / s;
            if (lane == i1) cacc += 1.0f;
            // top-2
            const float lm = (lane == i1) ? -1e30f : l;
            float m2 = lm; int i2 = lane;
            #pragma unroll
            for (int off = 32; off > 0; off >>= 1) {
                const float ov = __shfl_xor(m2, off, 64);
                const int   oi = __shfl_xor(i2, off, 64);
                if (ov > m2 || (ov == m2 && oi < i2)) { m2 = ov; i2 = oi; }
            }
            if (lane == 0) {
                out[2 * t]     = (float)i1;
                out[2 * t + 1] = (float)i2;
                const float w1 = 1.0f / (1.0f + __expf(m2 - m1));
                out[2 * M_TOK + 2 * t]     = w1;
                out[2 * M_TOK + 2 * t + 1] = 1.0f - w1;
            }
        }
    }
    __syncthreads();
    if (wid < 4) {
        lds[wid * 64 + lane]       = pacc;
        lds[256 + wid * 64 + lane] = cacc;
    }
    __syncthreads();
    if (wid == 0) {
        // same left-assoc 4-wave combine + one atomic per expert per 64-token block
        atomicAdd(&gprob[lane], lds[lane] + lds[64 + lane] + lds[128 + lane] + lds[192 + lane]);
        atomicAdd(&gcnt[lane],  lds[256 + lane] + lds[320 + lane] + lds[384 + lane] + lds[448 + lane]);
    }
}

__global__ __launch_bounds__(64) void aux_kernel(
    const float* __restrict__ gprob, const float* __restrict__ gcnt,
    float* __restrict__ out)
{
    const int lane = threadIdx.x;
    float v = gprob[lane] * gcnt[lane];
    #pragma unroll
    for (int off = 32; off > 0; off >>= 1) v += __shfl_xor(v, off, 64);
    if (lane == 0)
        out[4 * M_TOK] = 64.0f * 0.01f * v / ((float)M_TOK * (float)M_TOK);
}

extern "C" void kernel_launch(void* const* d_in, const int* in_sizes, int n_in,
                              void* d_out, int out_size, void* d_ws, size_t ws_size,
                              hipStream_t stream)
{
    const float* x = (const float*)d_in[0];
    const float* W = (const float*)d_in[1];
    float* out   = (float*)d_out;
    float* gprob = (float*)d_ws;
    float* gcnt  = gprob + 64;
    float* Wt    = gprob + 128;

    wt_kernel<<<128, 256, 0, stream>>>(W, Wt, gprob);
    fused_kernel<<<256, 1024, 0, stream>>>(x, Wt, out, gprob, gcnt);
    aux_kernel<<<1, 64, 0, stream>>>(gprob, gcnt, out);
}

// Round 6
// 429.494 us; speedup vs baseline: 1.0024x; 1.0024x over previous
//
#include <hip/hip_runtime.h>

#define D_DIM 2048
#define E_NUM 64
#define M_TOK 16384          // B*L = 4*4096
#define BK 32                // k per staged tile
#define XS_ROW 36            // 32 + 4 pad: 144B row stride -> rows 16B-aligned for
                             // ds_read_b128; 8 cyc/b128 wave access (minimum)
#define XS_TILE (64 * XS_ROW)   // 2304 floats per (half, buf)

// ws layout: gprob[64], gcnt[64], Wt[2048*64] (f32, [k][e])

// one-off transpose W[e][k] -> Wt[k][e]; block 0 also zeroes gprob/gcnt
__global__ __launch_bounds__(256) void wt_kernel(const float* __restrict__ W,
                                                 float* __restrict__ Wt,
                                                 float* __restrict__ g) {
    if (blockIdx.x == 0 && threadIdx.x < 128) g[threadIdx.x] = 0.0f;
    const int i4 = blockIdx.x * 256 + threadIdx.x;   // grid 128 -> 32768 float4s
    const int e  = i4 >> 9;                          // 0..63
    const int k4 = (i4 & 511) << 2;                  // 0..2044
    const float4 v = *(const float4*)&W[e * D_DIM + k4];
    Wt[(k4 + 0) * E_NUM + e] = v.x;
    Wt[(k4 + 1) * E_NUM + e] = v.y;
    Wt[(k4 + 2) * E_NUM + e] = v.z;
    Wt[(k4 + 3) * E_NUM + e] = v.w;
}

// block = 1024 threads = 16 waves; block owns 64 tokens (lane = token).
// wave w: k-half h = w>>3, experts [8*(w&7), +8).
// R5 lesson: __launch_bounds__(1024,1) let the occupancy heuristic target
// 2 blocks/CU (8 waves/EU) -> 64-VGPR cap -> W loads re-rolled into
// issue-wait-consume pairs -> latency exposed, VALUBusy 17%. The grid is 1
// block/CU, so that occupancy never exists. (1024, 4) pins the target to 4
// waves/EU (this one block) -> cap 128; demand ~110 (16 in-flight W float4
// = 64 + accd 16 + accc 8 + misc) fits, loads stay batched.
// R4 lesson (kept): vz asm-zero keeps W on the VECTOR memory path (uniform
// address -> broadcast via L1); readfirstlane scalarized it onto the single
// scalar pipe (SGPR=112, VALUBusy 31%).
// LDS union (9216 floats):
//   gemm phase: xs(h,buf) at (h*2+buf)*2304, [64 rows][36]
//   epilogue:   S(h) at h*4096 + t*64 + e  (after last loop barrier, xs dead)
//   reduction:  pacc [0..256), cacc [256..512)
__global__ __launch_bounds__(1024, 4) void fused_kernel(
    const float* __restrict__ x, const float* __restrict__ Wt,
    float* __restrict__ out, float* __restrict__ gprob, float* __restrict__ gcnt)
{
    __shared__ float lds[4 * XS_TILE];   // 36864 B

    const int tid  = threadIdx.x;
    const int wid  = tid >> 6;
    const int lane = tid & 63;           // token within block
    const int h    = wid >> 3;           // k-half
    const int eb   = (wid & 7) << 3;     // expert base (8 experts/wave)
    const long tok0 = (long)blockIdx.x * 64;

    // VGPR-held zero the compiler cannot fold: keeps W addressing divergent
    // -> global_load_dwordx4 (vector path), not s_load (scalar path).
    int vz;
    asm volatile("v_mov_b32 %0, 0" : "=v"(vz));
    const float* wbase = Wt + vz;

    // staging role: threads 0..511 stage half 0, 512..1023 stage half 1;
    // one float4 per thread per tile (64 rows x 32 k per half)
    const int sh   = tid >> 9;
    const int ss   = tid & 511;
    const int srow = ss >> 3;            // token row 0..63
    const int sc   = (ss & 7) << 2;      // k offset 0,4,...,28
    const float* xsrc = x + (tok0 + srow) * D_DIM + (sh << 10) + sc;

    double accd[8];
    #pragma unroll
    for (int e = 0; e < 8; ++e) accd[e] = 0.0;

    // ---- prologue: stage tile 0 ----
    float4 v0 = *(const float4*)(xsrc);
    *(float4*)&lds[(sh * 2) * XS_TILE + srow * XS_ROW + sc] = v0;
    __syncthreads();

    for (int it = 0; it < 32; ++it) {
        // issue next tile's global load early (HBM latency hides under compute)
        if (it < 31) v0 = *(const float4*)(xsrc + (it + 1) * BK);
        // ---- compute tile it from buf (it&1) ----
        const float* xb = lds + (h * 2 + (it & 1)) * XS_TILE + lane * XS_ROW;
        const int kb0 = (h << 10) + it * BK;
        #pragma unroll 1
        for (int c2 = 0; c2 < 2; ++c2) {     // two 16-k chunks (fold granularity)
            float accc[8];
            #pragma unroll
            for (int e = 0; e < 8; ++e) accc[e] = 0.0f;
            const float* xc = xb + c2 * 16;
            const float* wp = wbase + (size_t)(kb0 + c2 * 16) * E_NUM + eb;
            #pragma unroll 1
            for (int q = 0; q < 2; ++q) {    // 8-k batches bound W in flight
                const float4 xa  = *(const float4*)(xc + q * 8);
                const float4 xs4 = *(const float4*)(xc + q * 8 + 4);
                const float xr[8] = { xa.x, xa.y, xa.z, xa.w,
                                      xs4.x, xs4.y, xs4.z, xs4.w };
                float4 w0[8], w1[8];         // 16 float4 in flight (64 VGPR)
                #pragma unroll
                for (int k2 = 0; k2 < 8; ++k2) {
                    const float* wr = wp + (q * 8 + k2) * E_NUM;
                    w0[k2] = *(const float4*)(wr + 0);
                    w1[k2] = *(const float4*)(wr + 4);
                }
                // per-expert k ascending: q outer, k2 inner -> k 0..15 in order
                #pragma unroll
                for (int k2 = 0; k2 < 8; ++k2) {
                    const float xk = xr[k2];
                    accc[0] += xk * w0[k2].x;  accc[1] += xk * w0[k2].y;
                    accc[2] += xk * w0[k2].z;  accc[3] += xk * w0[k2].w;
                    accc[4] += xk * w1[k2].x;  accc[5] += xk * w1[k2].y;
                    accc[6] += xk * w1[k2].z;  accc[7] += xk * w1[k2].w;
                }
            }
            #pragma unroll
            for (int e = 0; e < 8; ++e) accd[e] += (double)accc[e];
        }
        // ---- write staged reg into the other buffer ----
        if (it < 31)
            *(float4*)&lds[(sh * 2 + ((it + 1) & 1)) * XS_TILE + srow * XS_ROW + sc] = v0;
        __syncthreads();
    }

    // ---- S overlay: per-half f32 partial logits (same split/cast as before) ----
    {
        float* sp = lds + h * 4096 + lane * 64 + eb;
        *(float4*)(sp + 0) = make_float4((float)accd[0], (float)accd[1],
                                         (float)accd[2], (float)accd[3]);
        *(float4*)(sp + 4) = make_float4((float)accd[4], (float)accd[5],
                                         (float)accd[6], (float)accd[7]);
    }
    __syncthreads();

    // ---- fused topk/softmax (waves 0..3; lane = expert; verbatim math) ----
    float pacc = 0.0f, cacc = 0.0f;
    if (wid < 4) {
        const int q = wid;
        for (int i = 0; i < 16; ++i) {
            const int  tl = q * 16 + i;
            const long t  = tok0 + tl;
            const float l = lds[tl * 64 + lane] + lds[4096 + tl * 64 + lane];
            // top-1 (max, lowest index on tie — matches jax.lax.top_k)
            float m1 = l; int i1 = lane;
            #pragma unroll
            for (int off = 32; off > 0; off >>= 1) {
                const float ov = __shfl_xor(m1, off, 64);
                const int   oi = __shfl_xor(i1, off, 64);
                if (ov > m1 || (ov == m1 && oi < i1)) { m1 = ov; i1 = oi; }
            }
            // full softmax prob for aux loss
            const float p = __expf(l - m1);
            float s = p;
            #pragma unroll
            for (int off = 32; off > 0; off >>= 1) s += __shfl_xor(s, off, 64);
            pacc += p / s;
            if (lane == i1) cacc += 1.0f;
            // top-2
            const float lm = (lane == i1) ? -1e30f : l;
            float m2 = lm; int i2 = lane;
            #pragma unroll
            for (int off = 32; off > 0; off >>= 1) {
                const float ov = __shfl_xor(m2, off, 64);
                const int   oi = __shfl_xor(i2, off, 64);
                if (ov > m2 || (ov == m2 && oi < i2)) { m2 = ov; i2 = oi; }
            }
            if (lane == 0) {
                out[2 * t]     = (float)i1;
                out[2 * t + 1] = (float)i2;
                const float w1 = 1.0f / (1.0f + __expf(m2 - m1));
                out[2 * M_TOK + 2 * t]     = w1;
                out[2 * M_TOK + 2 * t + 1] = 1.0f - w1;
            }
        }
    }
    __syncthreads();
    if (wid < 4) {
        lds[wid * 64 + lane]       = pacc;
        lds[256 + wid * 64 + lane] = cacc;
    }
    __syncthreads();
    if (wid == 0) {
        // same left-assoc 4-wave combine + one atomic per expert per 64-token block
        atomicAdd(&gprob[lane], lds[lane] + lds[64 + lane] + lds[128 + lane] + lds[192 + lane]);
        atomicAdd(&gcnt[lane],  lds[256 + lane] + lds[320 + lane] + lds[384 + lane] + lds[448 + lane]);
    }
}

__global__ __launch_bounds__(64) void aux_kernel(
    const float* __restrict__ gprob, const float* __restrict__ gcnt,
    float* __restrict__ out)
{
    const int lane = threadIdx.x;
    float v = gprob[lane] * gcnt[lane];
    #pragma unroll
    for (int off = 32; off > 0; off >>= 1) v += __shfl_xor(v, off, 64);
    if (lane == 0)
        out[4 * M_TOK] = 64.0f * 0.01f * v / ((float)M_TOK * (float)M_TOK);
}

extern "C" void kernel_launch(void* const* d_in, const int* in_sizes, int n_in,
                              void* d_out, int out_size, void* d_ws, size_t ws_size,
                              hipStream_t stream)
{
    const float* x = (const float*)d_in[0];
    const float* W = (const float*)d_in[1];
    float* out   = (float*)d_out;
    float* gprob = (float*)d_ws;
    float* gcnt  = gprob + 64;
    float* Wt    = gprob + 128;

    wt_kernel<<<128, 256, 0, stream>>>(W, Wt, gprob);
    fused_kernel<<<256, 1024, 0, stream>>>(x, Wt, out, gprob, gcnt);
    aux_kernel<<<1, 64, 0, stream>>>(gprob, gcnt, out);
}

// Round 7
// 428.746 us; speedup vs baseline: 1.0042x; 1.0017x over previous
//
#include <hip/hip_runtime.h>

#define D_DIM 2048
#define E_NUM 64
#define M_TOK 16384          // B*L = 4*4096
#define BK 32                // k per staged tile
#define XS_ROW 36            // 32 + 4 pad: 144B row stride -> rows 16B-aligned for
                             // ds_read_b128; 8 cyc/b128 wave access (minimum)
#define XS_TILE (64 * XS_ROW)   // 2304 floats per (half, buf)

// ws layout: gprob[64], gcnt[64], Wt[2048*64] (f32, [k][e])

// one-off transpose W[e][k] -> Wt[k][e]; block 0 also zeroes gprob/gcnt
__global__ __launch_bounds__(256) void wt_kernel(const float* __restrict__ W,
                                                 float* __restrict__ Wt,
                                                 float* __restrict__ g) {
    if (blockIdx.x == 0 && threadIdx.x < 128) g[threadIdx.x] = 0.0f;
    const int i4 = blockIdx.x * 256 + threadIdx.x;   // grid 128 -> 32768 float4s
    const int e  = i4 >> 9;                          // 0..63
    const int k4 = (i4 & 511) << 2;                  // 0..2044
    const float4 v = *(const float4*)&W[e * D_DIM + k4];
    Wt[(k4 + 0) * E_NUM + e] = v.x;
    Wt[(k4 + 1) * E_NUM + e] = v.y;
    Wt[(k4 + 2) * E_NUM + e] = v.z;
    Wt[(k4 + 3) * E_NUM + e] = v.w;
}

// block = 1024 threads = 16 waves; block owns 64 tokens (lane = token).
// wave w: k-half h = w>>3, experts [8*(w&7), +8).
// R6 lesson: __launch_bounds__(1024,4) sets only the MINIMUM waves/EU; the
// backend's own heuristic still targeted 8 waves/EU (2 blocks/CU by LDS) ->
// 64-VGPR self-cap -> W loads re-rolled, latency exposed, VALUBusy 17%.
// The grid is 1 block/CU so 8/EU never materializes. amdgpu_waves_per_eu(4,4)
// pins min AND MAX -> the allocator plans for 4 waves/EU = 128-VGPR budget;
// demand ~112 (16 in-flight W float4 = 64 + accd 16 + accc 8 + misc) fits.
// R4 lesson (kept): vz asm-zero keeps W on the VECTOR memory path (uniform
// address -> broadcast via L1); readfirstlane scalarized it onto the single
// scalar pipe (SGPR=112, VALUBusy 31%).
// LDS union (9216 floats):
//   gemm phase: xs(h,buf) at (h*2+buf)*2304, [64 rows][36]
//   epilogue:   S(h) at h*4096 + t*64 + e  (after last loop barrier, xs dead)
//   reduction:  pacc [0..256), cacc [256..512)
__global__
__attribute__((amdgpu_flat_work_group_size(1024, 1024)))
__attribute__((amdgpu_waves_per_eu(4, 4)))
void fused_kernel(
    const float* __restrict__ x, const float* __restrict__ Wt,
    float* __restrict__ out, float* __restrict__ gprob, float* __restrict__ gcnt)
{
    __shared__ float lds[4 * XS_TILE];   // 36864 B

    const int tid  = threadIdx.x;
    const int wid  = tid >> 6;
    const int lane = tid & 63;           // token within block
    const int h    = wid >> 3;           // k-half
    const int eb   = (wid & 7) << 3;     // expert base (8 experts/wave)
    const long tok0 = (long)blockIdx.x * 64;

    // VGPR-held zero the compiler cannot fold: keeps W addressing divergent
    // -> global_load_dwordx4 (vector path), not s_load (scalar path).
    int vz;
    asm volatile("v_mov_b32 %0, 0" : "=v"(vz));
    const float* wbase = Wt + vz;

    // staging role: threads 0..511 stage half 0, 512..1023 stage half 1;
    // one float4 per thread per tile (64 rows x 32 k per half)
    const int sh   = tid >> 9;
    const int ss   = tid & 511;
    const int srow = ss >> 3;            // token row 0..63
    const int sc   = (ss & 7) << 2;      // k offset 0,4,...,28
    const float* xsrc = x + (tok0 + srow) * D_DIM + (sh << 10) + sc;

    double accd[8];
    #pragma unroll
    for (int e = 0; e < 8; ++e) accd[e] = 0.0;

    // ---- prologue: stage tile 0 ----
    float4 v0 = *(const float4*)(xsrc);
    *(float4*)&lds[(sh * 2) * XS_TILE + srow * XS_ROW + sc] = v0;
    __syncthreads();

    for (int it = 0; it < 32; ++it) {
        // issue next tile's global load early (HBM latency hides under compute)
        if (it < 31) v0 = *(const float4*)(xsrc + (it + 1) * BK);
        // ---- compute tile it from buf (it&1) ----
        const float* xb = lds + (h * 2 + (it & 1)) * XS_TILE + lane * XS_ROW;
        const int kb0 = (h << 10) + it * BK;
        #pragma unroll 1
        for (int c2 = 0; c2 < 2; ++c2) {     // two 16-k chunks (fold granularity)
            float accc[8];
            #pragma unroll
            for (int e = 0; e < 8; ++e) accc[e] = 0.0f;
            const float* xc = xb + c2 * 16;
            const float* wp = wbase + (size_t)(kb0 + c2 * 16) * E_NUM + eb;
            #pragma unroll 1
            for (int q = 0; q < 2; ++q) {    // 8-k batches bound W in flight
                const float4 xa  = *(const float4*)(xc + q * 8);
                const float4 xs4 = *(const float4*)(xc + q * 8 + 4);
                const float xr[8] = { xa.x, xa.y, xa.z, xa.w,
                                      xs4.x, xs4.y, xs4.z, xs4.w };
                float4 w0[8], w1[8];         // 16 float4 in flight (64 VGPR)
                #pragma unroll
                for (int k2 = 0; k2 < 8; ++k2) {
                    const float* wr = wp + (q * 8 + k2) * E_NUM;
                    w0[k2] = *(const float4*)(wr + 0);
                    w1[k2] = *(const float4*)(wr + 4);
                }
                // per-expert k ascending: q outer, k2 inner -> k 0..15 in order
                #pragma unroll
                for (int k2 = 0; k2 < 8; ++k2) {
                    const float xk = xr[k2];
                    accc[0] += xk * w0[k2].x;  accc[1] += xk * w0[k2].y;
                    accc[2] += xk * w0[k2].z;  accc[3] += xk * w0[k2].w;
                    accc[4] += xk * w1[k2].x;  accc[5] += xk * w1[k2].y;
                    accc[6] += xk * w1[k2].z;  accc[7] += xk * w1[k2].w;
                }
            }
            #pragma unroll
            for (int e = 0; e < 8; ++e) accd[e] += (double)accc[e];
        }
        // ---- write staged reg into the other buffer ----
        if (it < 31)
            *(float4*)&lds[(sh * 2 + ((it + 1) & 1)) * XS_TILE + srow * XS_ROW + sc] = v0;
        __syncthreads();
    }

    // ---- S overlay: per-half f32 partial logits (same split/cast as before) ----
    {
        float* sp = lds + h * 4096 + lane * 64 + eb;
        *(float4*)(sp + 0) = make_float4((float)accd[0], (float)accd[1],
                                         (float)accd[2], (float)accd[3]);
        *(float4*)(sp + 4) = make_float4((float)accd[4], (float)accd[5],
                                         (float)accd[6], (float)accd[7]);
    }
    __syncthreads();

    // ---- fused topk/softmax (waves 0..3; lane = expert; verbatim math) ----
    float pacc = 0.0f, cacc = 0.0f;
    if (wid < 4) {
        const int q = wid;
        for (int i = 0; i < 16; ++i) {
            const int  tl = q * 16 + i;
            const long t  = tok0 + tl;
            const float l = lds[tl * 64 + lane] + lds[4096 + tl * 64 + lane];
            // top-1 (max, lowest index on tie — matches jax.lax.top_k)
            float m1 = l; int i1 = lane;
            #pragma unroll
            for (int off = 32; off > 0; off >>= 1) {
                const float ov = __shfl_xor(m1, off, 64);
                const int   oi = __shfl_xor(i1, off, 64);
                if (ov > m1 || (ov == m1 && oi < i1)) { m1 = ov; i1 = oi; }
            }
            // full softmax prob for aux loss
            const float p = __expf(l - m1);
            float s = p;
            #pragma unroll
            for (int off = 32; off > 0; off >>= 1) s += __shfl_xor(s, off, 64);
            pacc += p / s;
            if (lane == i1) cacc += 1.0f;
            // top-2
            const float lm = (lane == i1) ? -1e30f : l;
            float m2 = lm; int i2 = lane;
            #pragma unroll
            for (int off = 32; off > 0; off >>= 1) {
                const float ov = __shfl_xor(m2, off, 64);
                const int   oi = __shfl_xor(i2, off, 64);
                if (ov > m2 || (ov == m2 && oi < i2)) { m2 = ov; i2 = oi; }
            }
            if (lane == 0) {
                out[2 * t]     = (float)i1;
                out[2 * t + 1] = (float)i2;
                const float w1 = 1.0f / (1.0f + __expf(m2 - m1));
                out[2 * M_TOK + 2 * t]     = w1;
                out[2 * M_TOK + 2 * t + 1] = 1.0f - w1;
            }
        }
    }
    __syncthreads();
    if (wid < 4) {
        lds[wid * 64 + lane]       = pacc;
        lds[256 + wid * 64 + lane] = cacc;
    }
    __syncthreads();
    if (wid == 0) {
        // same left-assoc 4-wave combine + one atomic per expert per 64-token block
        atomicAdd(&gprob[lane], lds[lane] + lds[64 + lane] + lds[128 + lane] + lds[192 + lane]);
        atomicAdd(&gcnt[lane],  lds[256 + lane] + lds[320 + lane] + lds[384 + lane] + lds[448 + lane]);
    }
}

__global__ __launch_bounds__(64) void aux_kernel(
    const float* __restrict__ gprob, const float* __restrict__ gcnt,
    float* __restrict__ out)
{
    const int lane = threadIdx.x;
    float v = gprob[lane] * gcnt[lane];
    #pragma unroll
    for (int off = 32; off > 0; off >>= 1) v += __shfl_xor(v, off, 64);
    if (lane == 0)
        out[4 * M_TOK] = 64.0f * 0.01f * v / ((float)M_TOK * (float)M_TOK);
}

extern "C" void kernel_launch(void* const* d_in, const int* in_sizes, int n_in,
                              void* d_out, int out_size, void* d_ws, size_t ws_size,
                              hipStream_t stream)
{
    const float* x = (const float*)d_in[0];
    const float* W = (const float*)d_in[1];
    float* out   = (float*)d_out;
    float* gprob = (float*)d_ws;
    float* gcnt  = gprob + 64;
    float* Wt    = gprob + 128;

    wt_kernel<<<128, 256, 0, stream>>>(W, Wt, gprob);
    fused_kernel<<<256, 1024, 0, stream>>>(x, Wt, out, gprob, gcnt);
    aux_kernel<<<1, 64, 0, stream>>>(gprob, gcnt, out);
}

// Round 8
// 259.563 us; speedup vs baseline: 1.6587x; 1.6518x over previous
//
#include <hip/hip_runtime.h>

typedef float f32x16 __attribute__((ext_vector_type(16)));

#define D_DIM 2048
#define E_NUM 64
#define M_TOK 16384          // B*L = 4*4096
#define BK 32                // k per staged tile
#define XS_ROW 36            // 32 + 4 pad: 144B rows keep 16B alignment for b128
#define XS_TILE (64 * XS_ROW)   // 2304 floats per (half, buf)

// ws layout: gprob[64], gcnt[64], pad to 512B, Wg[2][8][1024][8] f32 (512 KB)
// Wg[h][g][kk][e'] = W[g*8+e'][h*1024+kk]: each wave's 16-k chunk of its 8
// experts is 512 CONTIGUOUS bytes -> s_load_dwordx16-mergeable.

// one-off shuffle W[e][k] -> Wg; block 0 also zeroes gprob/gcnt
__global__ __launch_bounds__(256) void wg_kernel(const float* __restrict__ W,
                                                 float* __restrict__ Wg,
                                                 float* __restrict__ g) {
    if (blockIdx.x == 0 && threadIdx.x < 128) g[threadIdx.x] = 0.0f;
    const int i4 = blockIdx.x * 256 + threadIdx.x;   // grid 128 -> 32768 float4s
    const int e  = i4 >> 9;                          // 0..63
    const int k4 = (i4 & 511) << 2;                  // 0..2044
    const float4 v = *(const float4*)&W[e * D_DIM + k4];
    const int base = (((k4 >> 10) << 3) + (e >> 3)) * 8192 + (k4 & 1023) * 8 + (e & 7);
    Wg[base + 0]  = v.x;
    Wg[base + 8]  = v.y;
    Wg[base + 16] = v.z;
    Wg[base + 24] = v.w;
}

// block = 1024 threads = 16 waves; block owns 64 tokens (lane = token).
// wave w: k-half h = w>>3, expert group g = w&7 (8 experts).
// R5-R7 lesson: the backend pins 16-wave blocks to a 64-VGPR budget (attributes
// can't raise it), so a vector-path W stream (needs ~96 VGPR in flight) gets
// re-rolled into issue-wait-consume pairs -> VALUBusy 17%. R3/R4 lesson: the
// SCALAR path (W in SGPRs, s_load) fits 64 VGPRs and runs parallel to VALU;
// its limiter was request count (unmergeable dwordx4 rows). This version:
// contiguous Wg layout -> s_load_dwordx16 (4x fewer requests), FMAs read W
// directly from SGPRs (1 SGPR operand per VALU instr is free). 8-k sub-batches
// (#pragma unroll 1) keep <=64 W-SGPRs live (file = 102).
// LDS union (9216 floats):
//   gemm phase: xs(h,buf) at (h*2+buf)*2304, [64 rows][36]
//   epilogue:   S(h) at h*4096 + t*64 + e  (after last loop barrier, xs dead)
//   reduction:  pacc [0..256), cacc [256..512)
__global__ __launch_bounds__(1024) void fused_kernel(
    const float* __restrict__ x, const float* __restrict__ Wg,
    float* __restrict__ out, float* __restrict__ gprob, float* __restrict__ gcnt)
{
    __shared__ float lds[4 * XS_TILE];   // 36864 B

    const int tid  = threadIdx.x;
    const int wid  = tid >> 6;
    const int lane = tid & 63;           // token within block
    const int h    = wid >> 3;           // k-half
    const int eb   = (wid & 7) << 3;     // expert base (8 experts/wave)
    const long tok0 = (long)blockIdx.x * 64;
    // wave-uniform float-offset of this wave's W slab (8192 floats): keep it
    // in an SGPR so Wg loads stay on the scalar pipe (R4 behavior, wanted here)
    const int wslab = __builtin_amdgcn_readfirstlane(((h << 3) + (wid & 7)) * 8192);

    // staging role: threads 0..511 stage half 0, 512..1023 stage half 1;
    // one float4 per thread per tile (64 rows x 32 k per half)
    const int sh   = tid >> 9;
    const int ss   = tid & 511;
    const int srow = ss >> 3;            // token row 0..63
    const int sc   = (ss & 7) << 2;      // k offset 0,4,...,28
    const float* xsrc = x + (tok0 + srow) * D_DIM + (sh << 10) + sc;

    double accd[8];
    #pragma unroll
    for (int e = 0; e < 8; ++e) accd[e] = 0.0;

    // ---- prologue: stage tile 0 ----
    float4 v0 = *(const float4*)(xsrc);
    *(float4*)&lds[(sh * 2) * XS_TILE + srow * XS_ROW + sc] = v0;
    __syncthreads();

    for (int it = 0; it < 32; ++it) {
        // issue next tile's global load early (HBM latency hides under compute)
        if (it < 31) v0 = *(const float4*)(xsrc + (it + 1) * BK);
        // ---- compute tile it from buf (it&1) ----
        const float* xb = lds + (h * 2 + (it & 1)) * XS_TILE + lane * XS_ROW;
        #pragma unroll 1
        for (int c2 = 0; c2 < 2; ++c2) {     // two 16-k chunks (fold granularity)
            float accc[8];
            #pragma unroll
            for (int e = 0; e < 8; ++e) accc[e] = 0.0f;
            const float* xc = xb + c2 * 16;
            // chunk = 128 contiguous floats = 8 x16 slots; slot j holds
            // k = 2j,2j+1 for experts 0..7: elem(k,e') = wp[j][(k&1)*8+e']
            const f32x16* wp = (const f32x16*)(Wg + wslab + it * 256 + c2 * 128);
            #pragma unroll 1
            for (int hc = 0; hc < 2; ++hc) { // 8-k sub-batch: 4 x16 = 64 SGPR
                const f32x16 wA = wp[hc * 4 + 0];
                const f32x16 wB = wp[hc * 4 + 1];
                const f32x16 wC = wp[hc * 4 + 2];
                const f32x16 wD = wp[hc * 4 + 3];
                const float4 xa = *(const float4*)(xc + hc * 8);
                const float4 xb4 = *(const float4*)(xc + hc * 8 + 4);
                // per-expert chain strictly k-ascending (same bits as before)
                #pragma unroll
                for (int e = 0; e < 8; ++e) {
                    float a = accc[e];
                    a += xa.x  * wA[e];
                    a += xa.y  * wA[8 + e];
                    a += xa.z  * wB[e];
                    a += xa.w  * wB[8 + e];
                    a += xb4.x * wC[e];
                    a += xb4.y * wC[8 + e];
                    a += xb4.z * wD[e];
                    a += xb4.w * wD[8 + e];
                    accc[e] = a;
                }
            }
            #pragma unroll
            for (int e = 0; e < 8; ++e) accd[e] += (double)accc[e];
        }
        // ---- write staged reg into the other buffer ----
        if (it < 31)
            *(float4*)&lds[(sh * 2 + ((it + 1) & 1)) * XS_TILE + srow * XS_ROW + sc] = v0;
        __syncthreads();
    }

    // ---- S overlay: per-half f32 partial logits (same split/cast as before) ----
    {
        float* sp = lds + h * 4096 + lane * 64 + eb;
        *(float4*)(sp + 0) = make_float4((float)accd[0], (float)accd[1],
                                         (float)accd[2], (float)accd[3]);
        *(float4*)(sp + 4) = make_float4((float)accd[4], (float)accd[5],
                                         (float)accd[6], (float)accd[7]);
    }
    __syncthreads();

    // ---- fused topk/softmax (waves 0..3; lane = expert; verbatim math) ----
    float pacc = 0.0f, cacc = 0.0f;
    if (wid < 4) {
        const int q = wid;
        for (int i = 0; i < 16; ++i) {
            const int  tl = q * 16 + i;
            const long t  = tok0 + tl;
            const float l = lds[tl * 64 + lane] + lds[4096 + tl * 64 + lane];
            // top-1 (max, lowest index on tie — matches jax.lax.top_k)
            float m1 = l; int i1 = lane;
            #pragma unroll
            for (int off = 32; off > 0; off >>= 1) {
                const float ov = __shfl_xor(m1, off, 64);
                const int   oi = __shfl_xor(i1, off, 64);
                if (ov > m1 || (ov == m1 && oi < i1)) { m1 = ov; i1 = oi; }
            }
            // full softmax prob for aux loss
            const float p = __expf(l - m1);
            float s = p;
            #pragma unroll
            for (int off = 32; off > 0; off >>= 1) s += __shfl_xor(s, off, 64);
            pacc += p / s;
            if (lane == i1) cacc += 1.0f;
            // top-2
            const float lm = (lane == i1) ? -1e30f : l;
            float m2 = lm; int i2 = lane;
            #pragma unroll
            for (int off = 32; off > 0; off >>= 1) {
                const float ov = __shfl_xor(m2, off, 64);
                const int   oi = __shfl_xor(i2, off, 64);
                if (ov > m2 || (ov == m2 && oi < i2)) { m2 = ov; i2 = oi; }
            }
            if (lane == 0) {
                out[2 * t]     = (float)i1;
                out[2 * t + 1] = (float)i2;
                const float w1 = 1.0f / (1.0f + __expf(m2 - m1));
                out[2 * M_TOK + 2 * t]     = w1;
                out[2 * M_TOK + 2 * t + 1] = 1.0f - w1;
            }
        }
    }
    __syncthreads();
    if (wid < 4) {
        lds[wid * 64 + lane]       = pacc;
        lds[256 + wid * 64 + lane] = cacc;
    }
    __syncthreads();
    if (wid == 0) {
        // same left-assoc 4-wave combine + one atomic per expert per 64-token block
        atomicAdd(&gprob[lane], lds[lane] + lds[64 + lane] + lds[128 + lane] + lds[192 + lane]);
        atomicAdd(&gcnt[lane],  lds[256 + lane] + lds[320 + lane] + lds[384 + lane] + lds[448 + lane]);
    }
}

__global__ __launch_bounds__(64) void aux_kernel(
    const float* __restrict__ gprob, const float* __restrict__ gcnt,
    float* __restrict__ out)
{
    const int lane = threadIdx.x;
    float v = gprob[lane] * gcnt[lane];
    #pragma unroll
    for (int off = 32; off > 0; off >>= 1) v += __shfl_xor(v, off, 64);
    if (lane == 0)
        out[4 * M_TOK] = 64.0f * 0.01f * v / ((float)M_TOK * (float)M_TOK);
}

extern "C" void kernel_launch(void* const* d_in, const int* in_sizes, int n_in,
                              void* d_out, int out_size, void* d_ws, size_t ws_size,
                              hipStream_t stream)
{
    const float* x = (const float*)d_in[0];
    const float* W = (const float*)d_in[1];
    float* out   = (float*)d_out;
    float* gprob = (float*)d_ws;
    float* gcnt  = gprob + 64;
    float* Wg    = gprob + 128;   // 512B offset, 64B-aligned for s_load_dwordx16

    wg_kernel<<<128, 256, 0, stream>>>(W, Wg, gprob);
    fused_kernel<<<256, 1024, 0, stream>>>(x, Wg, out, gprob, gcnt);
    aux_kernel<<<1, 64, 0, stream>>>(gprob, gcnt, out);
}